// Round 3
// baseline (1401.317 us; speedup 1.0000x reference)
//
#include <hip/hip_runtime.h>
#include <cstddef>

#define SCALE_F 0.17677669529663687f   // 1/sqrt(32)

// ---------------------------------------------------------------------------
// Kernel 1: fused QKV projection.  out[i][j] = sum_d x[i][d]*W[j][d] + b[j]
// scattered into [B][H][N][DK] layout.  Tile 64x64, 256 thr, 4x4 micro.
// ---------------------------------------------------------------------------
__global__ __launch_bounds__(256) void qkv_gemm(
    const float* __restrict__ x,
    const float* __restrict__ Wq, const float* __restrict__ bq,
    const float* __restrict__ Wk, const float* __restrict__ bk,
    const float* __restrict__ Wv, const float* __restrict__ bv,
    float* __restrict__ Qbuf, float* __restrict__ Kbuf, float* __restrict__ Vbuf)
{
    __shared__ float As[64][68];
    __shared__ float Bs[64][68];
    const int i0  = blockIdx.x * 64;
    const int bj  = blockIdx.y;          // 0..11
    const int wsel = bj >> 2;            // 0=Q 1=K 2=V
    const int jb  = (bj & 3) * 64;
    const float* __restrict__ W    = (wsel == 0) ? Wq : (wsel == 1) ? Wk : Wv;
    const float* __restrict__ bias = (wsel == 0) ? bq : (wsel == 1) ? bk : bv;
    float* __restrict__ out        = (wsel == 0) ? Qbuf : (wsel == 1) ? Kbuf : Vbuf;

    const int t  = threadIdx.x;
    const int tr = t >> 4, tc = t & 15;

    float acc[4][4] = {};

    for (int d0 = 0; d0 < 256; d0 += 64) {
        #pragma unroll
        for (int ph = 0; ph < 4; ++ph) {
            int id = ph * 256 + t;
            int r  = id >> 4;
            int c4 = (id & 15) << 2;
            *(float4*)&As[r][c4] = *(const float4*)&x[(size_t)(i0 + r) * 256 + d0 + c4];
            *(float4*)&Bs[r][c4] = *(const float4*)&W[(size_t)(jb + r) * 256 + d0 + c4];
        }
        __syncthreads();
        #pragma unroll 4
        for (int dd = 0; dd < 64; dd += 4) {
            float4 av[4], bv4[4];
            #pragma unroll
            for (int ii = 0; ii < 4; ++ii) av[ii]  = *(float4*)&As[tr + 16*ii][dd];
            #pragma unroll
            for (int jj = 0; jj < 4; ++jj) bv4[jj] = *(float4*)&Bs[tc + 16*jj][dd];
            #pragma unroll
            for (int ii = 0; ii < 4; ++ii)
                #pragma unroll
                for (int jj = 0; jj < 4; ++jj)
                    acc[ii][jj] += av[ii].x*bv4[jj].x + av[ii].y*bv4[jj].y
                                 + av[ii].z*bv4[jj].z + av[ii].w*bv4[jj].w;
        }
        __syncthreads();
    }

    #pragma unroll
    for (int ii = 0; ii < 4; ++ii) {
        int i  = i0 + tr + 16*ii;
        int b_ = i >> 10, n = i & 1023;
        #pragma unroll
        for (int jj = 0; jj < 4; ++jj) {
            int j  = jb + tc + 16*jj;
            int hh = j >> 5, dk = j & 31;
            out[(((size_t)(b_*8 + hh)) * 1024 + n) * 32 + dk] = acc[ii][jj] + bias[j];
        }
    }
}

// ---------------------------------------------------------------------------
// Kernel 2: fused flash attention, k-split-16 layout.
// grid = 2048 blocks (XCD-swizzled), block 256 = 4 waves.
// Block owns 16 q-rows of one (b,h); wave owns 4 rows; lane = (qr, ks):
// qr = lane>>4 (row within wave), ks = lane&15 (64-k slice).
// Each lane: full Q row + O[32] in VGPRs, online softmax over its 64 k
// (4 sub-tiles of 16).  Bias reads are 256 B contiguous per lane (full
// granule consumption).  K/V rows are 4-way-broadcast float4 loads,
// L2-resident via the XCD swizzle.  Final merge across the 16 k-slices is
// a 4-step __shfl_xor butterfly (m, l, O[32]) -- no LDS.
// Masked scores = -1e38; online softmax self-corrects; fully-masked row
// (m <= -1e37 after merge) writes 0 (nan_to_num semantics).
// ---------------------------------------------------------------------------
__global__ __launch_bounds__(256, 4) void attn_kernel(
    const float* __restrict__ Qbuf, const float* __restrict__ Kbuf,
    const float* __restrict__ Vbuf,
    const float* __restrict__ ebias, const float* __restrict__ sbias,
    const float* __restrict__ rbias,
    const int* __restrict__ mask, float* __restrict__ attout)
{
    // XCD swizzle: all 64 q-blocks of one (b,h) land on one XCD.
    const int id  = blockIdx.x;          // 0..2047
    const int xcd = id & 7;
    const int jj_ = id >> 3;             // 0..255
    const int bh  = xcd * 4 + (jj_ >> 6);  // 0..31
    const int qb  = jj_ & 63;            // 0..63  (16-row q blocks)
    const int b   = bh >> 3, h = bh & 7;

    const int t    = threadIdx.x;
    const int w    = t >> 6, lane = t & 63;
    const int qr   = lane >> 4;          // 0..3
    const int ks   = lane & 15;          // 0..15
    const int q    = qb * 16 + w * 4 + qr;
    const int kbase = ks * 64;

    // Q row, pre-scaled
    const float* __restrict__ qp = Qbuf + ((size_t)bh * 1024 + q) * 32;
    float Qs[32];
    #pragma unroll
    for (int i = 0; i < 8; ++i) {
        float4 v = *(const float4*)(qp + 4*i);
        Qs[4*i+0] = v.x * SCALE_F; Qs[4*i+1] = v.y * SCALE_F;
        Qs[4*i+2] = v.z * SCALE_F; Qs[4*i+3] = v.w * SCALE_F;
    }

    float O[32];
    #pragma unroll
    for (int d = 0; d < 32; ++d) O[d] = 0.f;
    float m = -1e38f, l = 0.f;

    const size_t rowbase = ((size_t)bh * 1024 + q) * 1024;
    const float* __restrict__ ebp = ebias + rowbase + kbase;
    const float* __restrict__ sbp = sbias + rowbase + kbase;
    const float* __restrict__ rbp = rbias + rowbase + kbase;
    const int*   __restrict__ mp  = mask + b * 1024 + kbase;
    const float* __restrict__ Kb  = Kbuf + ((size_t)bh * 1024 + kbase) * 32;
    const float* __restrict__ Vb  = Vbuf + ((size_t)bh * 1024 + kbase) * 32;

    for (int kt = 0; kt < 4; ++kt) {        // 4 sub-tiles of 16 k
        const int k0 = kt * 16;
        float s[16];
        #pragma unroll
        for (int i = 0; i < 4; ++i) {
            float4 e4 = *(const float4*)(ebp + k0 + 4*i);
            float4 s4 = *(const float4*)(sbp + k0 + 4*i);
            float4 r4 = *(const float4*)(rbp + k0 + 4*i);
            int4   m4 = *(const int4*)(mp + k0 + 4*i);
            s[4*i+0] = m4.x ? -1e38f : (e4.x + s4.x + r4.x);
            s[4*i+1] = m4.y ? -1e38f : (e4.y + s4.y + r4.y);
            s[4*i+2] = m4.z ? -1e38f : (e4.z + s4.z + r4.z);
            s[4*i+3] = m4.w ? -1e38f : (e4.w + s4.w + r4.w);
        }
        // QK^T (4 partial sums break the dependent FMA chain)
        #pragma unroll
        for (int kk = 0; kk < 16; ++kk) {
            const float4* kr = (const float4*)(Kb + (size_t)(k0 + kk) * 32);
            float4 k0v = kr[0], k1v = kr[1], k2v = kr[2], k3v = kr[3];
            float4 k4v = kr[4], k5v = kr[5], k6v = kr[6], k7v = kr[7];
            float d0 = Qs[0]*k0v.x + Qs[1]*k0v.y + Qs[2]*k0v.z + Qs[3]*k0v.w
                     + Qs[4]*k1v.x + Qs[5]*k1v.y + Qs[6]*k1v.z + Qs[7]*k1v.w;
            float d1 = Qs[8]*k2v.x + Qs[9]*k2v.y + Qs[10]*k2v.z + Qs[11]*k2v.w
                     + Qs[12]*k3v.x + Qs[13]*k3v.y + Qs[14]*k3v.z + Qs[15]*k3v.w;
            float d2 = Qs[16]*k4v.x + Qs[17]*k4v.y + Qs[18]*k4v.z + Qs[19]*k4v.w
                     + Qs[20]*k5v.x + Qs[21]*k5v.y + Qs[22]*k5v.z + Qs[23]*k5v.w;
            float d3 = Qs[24]*k6v.x + Qs[25]*k6v.y + Qs[26]*k6v.z + Qs[27]*k6v.w
                     + Qs[28]*k7v.x + Qs[29]*k7v.y + Qs[30]*k7v.z + Qs[31]*k7v.w;
            s[kk] += (d0 + d1) + (d2 + d3);
        }
        // online softmax update
        float tm = s[0];
        #pragma unroll
        for (int kk = 1; kk < 16; ++kk) tm = fmaxf(tm, s[kk]);
        float mnew = fmaxf(m, tm);
        float sc = __expf(m - mnew);
        m = mnew;
        l *= sc;
        #pragma unroll
        for (int d = 0; d < 32; ++d) O[d] *= sc;
        // PV
        #pragma unroll
        for (int kk = 0; kk < 16; ++kk) {
            float p = __expf(s[kk] - m);
            l += p;
            const float4* vr = (const float4*)(Vb + (size_t)(k0 + kk) * 32);
            #pragma unroll
            for (int i = 0; i < 8; ++i) {
                float4 vv = vr[i];
                O[4*i+0] += p * vv.x; O[4*i+1] += p * vv.y;
                O[4*i+2] += p * vv.z; O[4*i+3] += p * vv.w;
            }
        }
    }

    // butterfly merge across the 16 k-slices (lane bits 0..3)
    #pragma unroll
    for (int mk = 1; mk <= 8; mk <<= 1) {
        float om = __shfl_xor(m, mk, 64);
        float ol = __shfl_xor(l, mk, 64);
        float M  = fmaxf(m, om);
        float a  = __expf(m - M);
        float bb = __expf(om - M);
        l = a * l + bb * ol;
        #pragma unroll
        for (int d = 0; d < 32; ++d) {
            float oo = __shfl_xor(O[d], mk, 64);
            O[d] = a * O[d] + bb * oo;
        }
        m = M;
    }

    // lane ks==0 of each row writes the result (static indices, no scratch)
    if (ks == 0) {
        float inv = (m <= -1e37f) ? 0.f : 1.f / l;
        float* __restrict__ op = attout + ((size_t)(b * 1024 + q)) * 256 + h * 32;
        #pragma unroll
        for (int i = 0; i < 8; ++i) {
            float4 r;
            r.x = O[4*i+0] * inv; r.y = O[4*i+1] * inv;
            r.z = O[4*i+2] * inv; r.w = O[4*i+3] * inv;
            *(float4*)(op + 4*i) = r;
        }
    }
}

// ---------------------------------------------------------------------------
// Kernel 3: output projection.  out[i][j] = sum_d A[i][d]*Wo[j][d] + bo[j]
// ---------------------------------------------------------------------------
__global__ __launch_bounds__(256) void oproj_gemm(
    const float* __restrict__ A, const float* __restrict__ W,
    const float* __restrict__ bias, float* __restrict__ out)
{
    __shared__ float As[64][68];
    __shared__ float Bs[64][68];
    const int i0 = blockIdx.x * 64;
    const int jb = blockIdx.y * 64;
    const int t  = threadIdx.x;
    const int tr = t >> 4, tc = t & 15;
    float acc[4][4] = {};

    for (int d0 = 0; d0 < 256; d0 += 64) {
        #pragma unroll
        for (int ph = 0; ph < 4; ++ph) {
            int id = ph * 256 + t;
            int r  = id >> 4;
            int c4 = (id & 15) << 2;
            *(float4*)&As[r][c4] = *(const float4*)&A[(size_t)(i0 + r) * 256 + d0 + c4];
            *(float4*)&Bs[r][c4] = *(const float4*)&W[(size_t)(jb + r) * 256 + d0 + c4];
        }
        __syncthreads();
        #pragma unroll 4
        for (int dd = 0; dd < 64; dd += 4) {
            float4 av[4], bv4[4];
            #pragma unroll
            for (int ii = 0; ii < 4; ++ii) av[ii]  = *(float4*)&As[tr + 16*ii][dd];
            #pragma unroll
            for (int jj = 0; jj < 4; ++jj) bv4[jj] = *(float4*)&Bs[tc + 16*jj][dd];
            #pragma unroll
            for (int ii = 0; ii < 4; ++ii)
                #pragma unroll
                for (int jj = 0; jj < 4; ++jj)
                    acc[ii][jj] += av[ii].x*bv4[jj].x + av[ii].y*bv4[jj].y
                                 + av[ii].z*bv4[jj].z + av[ii].w*bv4[jj].w;
        }
        __syncthreads();
    }

    #pragma unroll
    for (int ii = 0; ii < 4; ++ii) {
        int i = i0 + tr + 16*ii;
        #pragma unroll
        for (int jj = 0; jj < 4; ++jj) {
            int j = jb + tc + 16*jj;
            out[(size_t)i * 256 + j] = acc[ii][jj] + bias[j];
        }
    }
}

// ---------------------------------------------------------------------------
extern "C" void kernel_launch(void* const* d_in, const int* in_sizes, int n_in,
                              void* d_out, int out_size, void* d_ws, size_t ws_size,
                              hipStream_t stream)
{
    const float* x     = (const float*)d_in[0];
    const float* ebias = (const float*)d_in[1];
    const float* sbias = (const float*)d_in[2];
    const float* rbias = (const float*)d_in[3];
    const int*   mask  = (const int*)d_in[4];
    const float* Wq = (const float*)d_in[5];  const float* bq = (const float*)d_in[6];
    const float* Wk = (const float*)d_in[7];  const float* bk = (const float*)d_in[8];
    const float* Wv = (const float*)d_in[9];  const float* bv = (const float*)d_in[10];
    const float* Wo = (const float*)d_in[11]; const float* bo = (const float*)d_in[12];
    float* out = (float*)d_out;

    float* ws = (float*)d_ws;
    float* Qbuf    = ws;                 // 4*8*1024*32 = 1048576 floats
    float* Kbuf    = ws + 1048576;
    float* Vbuf    = ws + 2097152;
    float* attnout = ws + 3145728;       // [B][N][D] = 1048576 floats

    qkv_gemm<<<dim3(64, 12), 256, 0, stream>>>(x, Wq, bq, Wk, bk, Wv, bv,
                                               Qbuf, Kbuf, Vbuf);
    attn_kernel<<<2048, 256, 0, stream>>>(Qbuf, Kbuf, Vbuf,
                                          ebias, sbias, rbias,
                                          mask, attnout);
    oproj_gemm<<<dim3(64, 4), 256, 0, stream>>>(attnout, Wo, bo, out);
}